// Round 17
// baseline (324.488 us; speedup 1.0000x reference)
//
#include <hip/hip_runtime.h>
#include <math.h>

// Problem constants
#define B_     8
#define S_     4
#define H_     50
#define NH_    200
#define EHH_   400
#define L_     2
#define HID_   128
#define FDIM_  79          // 44 + 20 + 15
#define EDIM_  161         // 2*FDIM + 3
#define NN_    250         // H + NH
#define NROW_  1600        // BS*H
#define BS_    32          // B*S
#define FS_    80          // feat row stride
#define MSTR_  136         // s_m stride in bf16 (128 + 8)
#define NDIM_  207         // FDIM + HID
#define HVB_   1600        // hjW1 heavy-region base row

// Workspace layout (float offsets) — double-buffered across layers:
//   x0 (l0 reads) -> x1 (l0 tail writes h-rows; l1 reads)
//   hiW1 rows [0,1600)=l0 (setup), [1600,3200)=l1 (l0 tail)
//   hjW1 rows [0,1600)=h l0 (setup), [1600,3200)=hv l0, [3200,4800)=hv l1 (setup),
//             [4800,6400)=h l1 (l0 tail)
#define OFF_FEATH  0         // 128000
#define OFF_X0     128000    // 32000
#define OFF_X1     160000    // 32000
#define OFF_X0H    192000    // 6400
#define OFF_HHCOL  198400    // 3200 (int)
#define OFF_HHEM   201600    // 3200
#define OFF_HHOFF  204800    // 512 (int)
#define OFF_HIW1   205312    // 3200*128 = 409600
#define OFF_HJW1   614912    // 6400*128 = 819200
#define OFF_WP     1434112   // 65536 ushort (16B-aligned)

typedef __attribute__((ext_vector_type(8))) short short8;
typedef __attribute__((ext_vector_type(4))) float f32x4;

__device__ __forceinline__ float silu_(float v) {
    return v * __builtin_amdgcn_rcpf(1.0f + __expf(-v));
}
__device__ __forceinline__ unsigned short f2bf(float f) {
    unsigned int u = __float_as_uint(f);
    unsigned int r = (u + 0x7fffu + ((u >> 16) & 1u)) >> 16;
    return (unsigned short)r;
}

// ================= fused setup (COMPACTED: 4 elements/thread, grid 2221 -> 562) =================
// R16 post-mortem: total - edge = ~57us for ~6MB of setup traffic (~2us at HBM).
// Hypothesis: block-count overhead (2221 tiny blocks). Per-element code verbatim,
// each block now covers 1024 elements via i=0..3 sub-iterations (coalescing kept).
#define HV_BLKS_    400    // 409600 / 1024
#define PACK_BLKS_  64     // 65536 / 1024
#define SORT_BLKS_  8      // counting-sort hh edges by row, per b; emits CSR
#define HROW_BLKS_  50     // 51200 / 1024
#define FEAT_BLKS_  32     // ceil(32000 / 1024)
#define XI_BLKS_    8      // ceil(8000 / 1024)
#define SETUP_BLKS_ (HV_BLKS_ + PACK_BLKS_ + SORT_BLKS_ + HROW_BLKS_ + FEAT_BLKS_ + XI_BLKS_)

__global__ __launch_bounds__(256) void k_setup(
    const float* __restrict__ x_h, const float* __restrict__ x_hv,
    const int* __restrict__ bound,
    const int* __restrict__ ehh, const float* __restrict__ em_hh,
    const float* __restrict__ W1, const float* __restrict__ b1,
    const float* __restrict__ t_in,
    const float* __restrict__ W2, const float* __restrict__ Wc1,
    const int* __restrict__ lab_h, const int* __restrict__ pos_h,
    const int* __restrict__ lab_hv, const int* __restrict__ pos_hv,
    const int* __restrict__ pep,
    float* __restrict__ feat_h,
    float* __restrict__ x0, float* __restrict__ x1, float* __restrict__ x0h,
    int* __restrict__ hhcol, float* __restrict__ hhem, int* __restrict__ hhoff,
    float* __restrict__ hiW1, float* __restrict__ hjW1,
    unsigned short* __restrict__ Wp)
{
    int blk = blockIdx.x, t = threadIdx.x;
    if (blk < HV_BLKS_) {
        #pragma unroll
        for (int i = 0; i < 4; ++i) {
            int g = blk*1024 + i*256 + t;    // [0, 409600)
            int l = g / 204800;
            int r = g - l*204800;
            int node = r >> 7, col = r & 127;    // node = b*NH + nh
            int b = node / NH_;
            int label = lab_hv[node], pos = pos_hv[node];
            int aa = pep[b*15 + pos - 1];
            const float* W1l = W1 + l*EDIM_*HID_;
            float hj = W1l[(FDIM_ + label)*HID_ + col]
                     + W1l[(FDIM_ + 44 + aa)*HID_ + col]
                     + W1l[(FDIM_ + 64 + pos - 1)*HID_ + col];
            hjW1[(size_t)(HVB_ + l*1600 + node)*HID_ + col] = hj;
        }
        return;
    }
    blk -= HV_BLKS_;
    if (blk < PACK_BLKS_) {
        // Pack W2/Wc1: ushort idx in a 16384 chunk = ((kc*8+nt)*64 + lane)*8 + j
        // -> a wave's (kc,nt) B-fragment read is one contiguous 1024B line.
        #pragma unroll
        for (int i = 0; i < 4; ++i) {
            int g = blk*1024 + i*256 + t;    // [0, 65536)
            int idx = g & 16383;
            int lm  = g >> 14;
            int l = lm >> 1, mat = lm & 1;
            int j   = idx & 7;
            int l15 = (idx >> 3) & 15;
            int qq  = (idx >> 7) & 3;
            int nt  = (idx >> 9) & 7;
            int kc  = (idx >> 12) & 3;
            int n = nt*16 + l15;
            int k = kc*32 + qq*8 + j;
            const float* W = (mat == 0 ? W2 : Wc1) + l*HID_*HID_;
            Wp[g] = f2bf(W[k*HID_ + n]);
        }
        return;
    }
    blk -= PACK_BLKS_;
    if (blk < SORT_BLKS_) {
        // counting-sort the 400 hh edges of batch b by row; emit CSR offsets
        int b = blk;
        __shared__ int scnt[64];
        __shared__ int srow[EHH_], scol[EHH_];
        __shared__ float sem[EHH_];
        if (t < 64) scnt[t] = 0;
        __syncthreads();
        for (int e = t; e < EHH_; e += 256) {
            int r = ehh[(b*EHH_ + e)*2 + 0];
            srow[e] = r;
            scol[e] = ehh[(b*EHH_ + e)*2 + 1];
            sem[e]  = em_hh[b*EHH_ + e];
            atomicAdd(&scnt[r], 1);
        }
        __syncthreads();
        if (t == 0) {
            int acc = 0;
            for (int i = 0; i < H_; ++i) { int v = scnt[i]; scnt[i] = acc; acc += v; }
        }
        __syncthreads();
        if (t < 51) hhoff[b*64 + t] = (t < H_) ? scnt[t] : EHH_;
        __syncthreads();
        for (int e = t; e < EHH_; e += 256) {
            int r = srow[e];
            int pos = atomicAdd(&scnt[r], 1);
            hhcol[b*EHH_ + pos] = scol[e];
            hhem [b*EHH_ + pos] = sem[e];
        }
        return;
    }
    blk -= SORT_BLKS_;
    if (blk < HROW_BLKS_) {
        // h-node layer-0 projections; fold b1 and t*w160 into hiW1
        #pragma unroll
        for (int i = 0; i < 4; ++i) {
            int g = blk*1024 + i*256 + t;    // [0, 51200)
            int node = g >> 7, col = g & 127;    // node = b*H + h
            int b = node / H_;
            int label = lab_h[node], pos = pos_h[node];
            int aa = pep[b*15 + pos - 1];
            const float* W1l = W1;               // layer 0
            float hi = W1l[label*HID_ + col]
                     + W1l[(44 + aa)*HID_ + col]
                     + W1l[(64 + pos - 1)*HID_ + col]
                     + b1[col]
                     + t_in[b] * W1l[160*HID_ + col];
            float hj = W1l[(FDIM_ + label)*HID_ + col]
                     + W1l[(FDIM_ + 44 + aa)*HID_ + col]
                     + W1l[(FDIM_ + 64 + pos - 1)*HID_ + col];
            int h = node % H_;
            #pragma unroll
            for (int s = 0; s < S_; ++s) {
                int row = (b*S_ + s)*H_ + h;
                hiW1[(size_t)row*HID_ + col] = hi;
                hjW1[(size_t)row*HID_ + col] = hj;
            }
        }
        return;
    }
    blk -= HROW_BLKS_;
    if (blk < FEAT_BLKS_) {
        #pragma unroll
        for (int i = 0; i < 4; ++i) {
            int g = blk*1024 + i*256 + t;    // [0, 32768) guard 32000
            if (g < 32000) {
                int node = g / FS_, f = g % FS_;     // node = b*H + h
                int b = node / H_, h = node % H_;
                int label = lab_h[node], pos = pos_h[node];
                int aa = pep[b*15 + pos - 1];
                float v = 0.f;
                if (f < 44)      v = (f == label)          ? 1.0f : 0.0f;
                else if (f < 64) v = ((f - 44) == aa)      ? 1.0f : 0.0f;
                else if (f < 79) v = ((f - 64) == pos - 1) ? 1.0f : 0.0f;
                #pragma unroll
                for (int s = 0; s < S_; ++s)
                    feat_h[((b*S_ + s)*H_ + h)*FS_ + f] = v;
            }
        }
        return;
    }
    blk -= FEAT_BLKS_;
    {
        #pragma unroll
        for (int i = 0; i < 4; ++i) {
            int g = blk*1024 + i*256 + t;    // [0, 8192) guard 8000
            if (g < BS_*NN_) {
                int bs = g / NN_, n = g % NN_;
                int b = bs / S_;
                if (n < H_) {
                    int ba = bound[b*H_ + n];
                    for (int d = 0; d < 3; ++d) {
                        float v = x_h[(bs*H_ + n)*3 + d] + x_hv[(b*NH_ + ba)*3 + d];
                        x0[g*4 + d] = v;
                        x0h[(bs*H_ + n)*4 + d] = v;
                    }
                } else {
                    int nh = n - H_;
                    for (int d = 0; d < 3; ++d) {
                        float v = x_hv[(b*NH_ + nh)*3 + d];
                        x0[g*4 + d] = v;
                        x1[g*4 + d] = v;         // heavy rows never change
                    }
                }
            }
        }
    }
}

// ============ per-layer: 8 rows/block, one wave per row; fused node-update tail ============
// FROZEN (verified 3x at 322.2/322.7/323.8 us). Design-space map, all HW-confirmed:
//   - dual-tile ILP (R12): needs ~190 VGPR -> spills at the 128 cap.
//   - 2 waves/row + Wp3->global (R15): LDS headroom raises occupancy target to
//     4 waves/EU -> register budget drops to 128 -> spills (168MB FETCH).
//   - this point (R13): 116 VGPR under the 2-wave/EU 256 budget, zero spill.
// The register budget is DERIVED from LDS-permitted occupancy on this toolchain
// (amdgpu_waves_per_eu ignored, R4); every added-concurrency direction shrinks
// the budget below the kernel's live set. Breaking this needs inline-asm-level
// register control.
__global__ __launch_bounds__(512) void k_edge_mlp(
    const float* __restrict__ xin, const float* __restrict__ hiW1g,
    const float* __restrict__ hjW1,
    const int* __restrict__ hhcol, const float* __restrict__ hhem,
    const int* __restrict__ hhoff,
    const float* __restrict__ em_hv, const float* __restrict__ bond_in,
    const float* __restrict__ W1,
    const float* __restrict__ b2, const float* __restrict__ bc1,
    const float* __restrict__ Wc2,
    const unsigned short* __restrict__ Wp, int l,
    const float* __restrict__ Wn1, const float* __restrict__ bn1,
    const float* __restrict__ Wn2, const float* __restrict__ bn2,
    const float* __restrict__ b1, const float* __restrict__ t_in,
    float* __restrict__ feat_h, float* __restrict__ xout,
    float* __restrict__ hiW1w, float* __restrict__ hjW1w,
    const float* __restrict__ x0h, const float* __restrict__ amask,
    float* __restrict__ out, int do_w1)
{
    __shared__ unsigned short s_wp[2*16384];       // 65536 B; fp32 scratch in tail
    __shared__ unsigned short s_m[8][16][MSTR_];   // 34816 B, wave-private 16-row chunks
    __shared__ float s_hi[8][HID_];                // 4096 B: per-row hiW1
    __shared__ float s_cc[5][HID_];                // W1r158, W1r159, b2, bc1, Wc2
    __shared__ float s_mr[8][HID_];                // 4096 B: per-row aggm
    __shared__ float s_xr[8][4];                   // per-row aggx

    const int t = threadIdx.x, lane = t & 63, w = t >> 6;
    const int l15 = lane & 15, q = lane >> 4;
    const int node0 = blockIdx.x*8;
    const int node  = node0 + w;                   // this wave's row (bs*H + h)
    const int bs = node / H_, h = node - bs*H_;
    const int b  = bs / S_;
    const int hb = (l ? 4800 : 0) + bs*H_;         // hjW1 h-region base for this layer

    // ---- stage weights Wp2|Wp3 (contiguous 64 KB) into LDS ----
    {
        const float4* src = (const float4*)(Wp + (size_t)l*32768);
        float4* dst = (float4*)s_wp;
        #pragma unroll
        for (int i = 0; i < 8; ++i) dst[t + i*512] = src[t + i*512];
    }
    const float* W1l = W1 + l*EDIM_*HID_;
    #pragma unroll
    for (int i = 0; i < 2; ++i) {
        int idx = i*512 + t;                       // [0,1024): 8 rows x 128 cols
        int g = idx >> 7, c = idx & 127;
        s_hi[g][c] = hiW1g[(size_t)(l*1600 + node0 + g)*HID_ + c];
    }
    if (t < 128) {
        s_cc[0][t] = W1l[158*HID_ + t];
        s_cc[1][t] = W1l[159*HID_ + t];
        s_cc[2][t] = b2 [l*HID_ + t];
        s_cc[3][t] = bc1[l*HID_ + t];
        s_cc[4][t] = Wc2[l*HID_ + t];
    }

    const int hh0 = hhoff[b*64 + h];
    const int cnt = hhoff[b*64 + h + 1] - hh0;
    const int E   = cnt + NH_;                     // total real edges for this row
    const int NT  = (E + 15) >> 4;                 // 16-edge tiles (13..14)

    const float xi0 = xin[(bs*NN_ + h)*4 + 0];
    const float xi1 = xin[(bs*NN_ + h)*4 + 1];
    const float xi2 = xin[(bs*NN_ + h)*4 + 2];

    // per-lane edge-scalar gather (executed by lanes 0..15 only)
    auto gather = [&](int e, float& d0, float& d1, float& d2,
                      float& dist, float& bnd, float& em, int& jj) {
        if (e < E) {
            int col;
            if (e < cnt) {                         // sorted hh edge
                col = hhcol[b*EHH_ + hh0 + e];
                em  = hhem [b*EHH_ + hh0 + e];
                jj  = hb + col;
            } else {                               // grid edge (row h -> heavy cc)
                int cc = e - cnt;
                col = H_ + cc;
                em  = em_hv [(b*H_ + h)*NH_ + cc];
                bnd = bond_in[(b*H_ + h)*NH_ + cc];
                jj  = HVB_ + l*1600 + b*NH_ + cc;
            }
            d0 = xi0 - xin[(bs*NN_ + col)*4 + 0];
            d1 = xi1 - xin[(bs*NN_ + col)*4 + 1];
            d2 = xi2 - xin[(bs*NN_ + col)*4 + 2];
            dist = sqrtf(d0*d0 + d1*d1 + d2*d2);
        }
    };

    float macc[8] = {0.f,0.f,0.f,0.f,0.f,0.f,0.f,0.f};
    float xacc = 0.f;
    __syncthreads();                               // s_wp/s_hi/s_cc ready

    // ---- pipeline prologue: tile 0 ----
    float cd0=0.f, cd1=0.f, cd2=0.f, cdist=0.f, cbnd=0.f, cem=0.f;
    int   cjj = hb;                                // padding: valid row, em=0
    if (lane < 16) gather(lane, cd0, cd1, cd2, cdist, cbnd, cem, cjj);
    float distb = __shfl(cdist, l15, 64);
    float bndb  = __shfl(cbnd,  l15, 64);
    int   jjb   = __shfl(cjj,   l15, 64);
    float4 pr[8];
    {
        const float* pj = hjW1 + (size_t)jjb*HID_ + q*8;
        #pragma unroll
        for (int kc = 0; kc < 4; ++kc) {
            pr[2*kc]   = *(const float4*)(pj + kc*32);
            pr[2*kc+1] = *(const float4*)(pj + kc*32 + 4);
        }
    }

    for (int ti = 0; ti < NT; ++ti) {
        const int nx = ti + 1;
        const bool hasNext = (nx < NT);            // wave-uniform

        // ---- gather NEXT tile's scalars (registers only) ----
        float nd0=0.f, nd1=0.f, nd2=0.f, ndist=0.f, nbnd=0.f, nem=0.f;
        int   njj = hb;
        if (hasNext && lane < 16)
            gather(nx*16 + lane, nd0, nd1, nd2, ndist, nbnd, nem, njj);

        // ---- stage 1: m1 = silu(hi + hj + dist*w158 + bond*w159) ----
        short8 afrag[4];
        #pragma unroll
        for (int kc = 0; kc < 4; ++kc) {
            int k0 = kc*32 + q*8;
            float4 c0 = pr[2*kc];
            float4 c1 = pr[2*kc+1];
            float4 h0 = *(const float4*)&s_hi[w][k0];
            float4 h1 = *(const float4*)&s_hi[w][k0 + 4];
            float4 wa0= *(const float4*)&s_cc[0][k0];
            float4 wa1= *(const float4*)&s_cc[0][k0 + 4];
            float4 wb0= *(const float4*)&s_cc[1][k0];
            float4 wb1= *(const float4*)&s_cc[1][k0 + 4];
            short8 fr;
            fr[0] = (short)f2bf(silu_(h0.x + c0.x + distb*wa0.x + bndb*wb0.x));
            fr[1] = (short)f2bf(silu_(h0.y + c0.y + distb*wa0.y + bndb*wb0.y));
            fr[2] = (short)f2bf(silu_(h0.z + c0.z + distb*wa0.z + bndb*wb0.z));
            fr[3] = (short)f2bf(silu_(h0.w + c0.w + distb*wa0.w + bndb*wb0.w));
            fr[4] = (short)f2bf(silu_(h1.x + c1.x + distb*wa1.x + bndb*wb1.x));
            fr[5] = (short)f2bf(silu_(h1.y + c1.y + distb*wa1.y + bndb*wb1.y));
            fr[6] = (short)f2bf(silu_(h1.z + c1.z + distb*wa1.z + bndb*wb1.z));
            fr[7] = (short)f2bf(silu_(h1.w + c1.w + distb*wa1.w + bndb*wb1.w));
            afrag[kc] = fr;
        }

        // ---- issue NEXT tile's hjW1 loads (hide under stage 2/3 MFMA) ----
        float ndistb = 0.f, nbndb = 0.f;
        if (hasNext) {
            ndistb = __shfl(ndist, l15, 64);
            nbndb  = __shfl(nbnd,  l15, 64);
            int njjb = __shfl(njj, l15, 64);
            const float* pj = hjW1 + (size_t)njjb*HID_ + q*8;
            #pragma unroll
            for (int kc = 0; kc < 4; ++kc) {
                pr[2*kc]   = *(const float4*)(pj + kc*32);
                pr[2*kc+1] = *(const float4*)(pj + kc*32 + 4);
            }
        }

        // ---- stage 2: m = silu(m1 @ W2 + b2) * emask; accumulate column sums ----
        float em4[4];
        #pragma unroll
        for (int rr = 0; rr < 4; ++rr) em4[rr] = __shfl(cem, q*4 + rr, 64);
        #pragma unroll
        for (int nt = 0; nt < 8; ++nt) {
            float bias = s_cc[2][nt*16 + l15];
            f32x4 c = {bias, bias, bias, bias};
            #pragma unroll
            for (int kc = 0; kc < 4; ++kc) {
                short8 bf = *(const short8*)&s_wp[((kc*8 + nt)*64 + lane)*8];
                c = __builtin_amdgcn_mfma_f32_16x16x32_bf16(afrag[kc], bf, c, 0, 0, 0);
            }
            #pragma unroll
            for (int rr = 0; rr < 4; ++rr) {
                float mv = silu_(c[rr]) * em4[rr]; // padding edges have em=0 -> mv=0
                s_m[w][q*4 + rr][nt*16 + l15] = f2bf(mv);
                macc[nt] += mv;
            }
        }
        __builtin_amdgcn_wave_barrier();           // s_m write -> read, wave-private

        // ---- stage 3: cw = silu(m @ Wc1 + bc1) @ Wc2; accumulate diff*cw ----
        short8 af2[4];
        #pragma unroll
        for (int kc = 0; kc < 4; ++kc)
            af2[kc] = *(const short8*)&s_m[w][l15][kc*32 + q*8];
        float p[4] = {0.f, 0.f, 0.f, 0.f};
        #pragma unroll
        for (int nt = 0; nt < 8; ++nt) {
            float bias = s_cc[3][nt*16 + l15];
            f32x4 c = {bias, bias, bias, bias};
            #pragma unroll
            for (int kc = 0; kc < 4; ++kc) {
                short8 bf = *(const short8*)&s_wp[16384 + ((kc*8 + nt)*64 + lane)*8];
                c = __builtin_amdgcn_mfma_f32_16x16x32_bf16(af2[kc], bf, c, 0, 0, 0);
            }
            float wcv = s_cc[4][nt*16 + l15];
            #pragma unroll
            for (int rr = 0; rr < 4; ++rr)
                p[rr] += silu_(c[rr]) * wcv;
        }
        #pragma unroll
        for (int m = 1; m < 16; m <<= 1) {
            #pragma unroll
            for (int rr = 0; rr < 4; ++rr) p[rr] += __shfl_xor(p[rr], m, 64);
        }
        #pragma unroll
        for (int rr = 0; rr < 4; ++rr) {
            float sd0 = __shfl(cd0, q*4 + rr, 64);
            float sd1 = __shfl(cd1, q*4 + rr, 64);
            float sd2 = __shfl(cd2, q*4 + rr, 64);
            if (l15 < 3) {
                float dsel = (l15 == 0) ? sd0 : ((l15 == 1) ? sd1 : sd2);
                xacc += dsel * p[rr];
            }
        }
        __builtin_amdgcn_wave_barrier();           // stage-3 s_m reads before next write

        // ---- rotate pipeline registers ----
        cd0 = nd0; cd1 = nd1; cd2 = nd2; cem = nem;
        distb = ndistb; bndb = nbndb;
    }

    // ---- intra-wave combine (wave == row: no cross-wave step) ----
    #pragma unroll
    for (int nt = 0; nt < 8; ++nt) {
        macc[nt] += __shfl_xor(macc[nt], 16, 64);
        macc[nt] += __shfl_xor(macc[nt], 32, 64);
    }
    if (q == 0) {
        #pragma unroll
        for (int nt = 0; nt < 8; ++nt) s_mr[w][nt*16 + l15] = macc[nt];
    }
    xacc += __shfl_xor(xacc, 16, 64);
    xacc += __shfl_xor(xacc, 32, 64);
    if (q == 0 && l15 < 3) s_xr[w][l15] = xacc;
    __syncthreads();                               // edge work done; s_wp now dead

    // ================= FUSED node update (8 rows, 512 threads) =================
    // Full-width GEMV tasks (no k-split): compile-time trip counts + unroll 8.
    float* su = (float*)s_wp;                      // 16384 floats of scratch
    // su[0..1664): s_in[8][208] | su[2048..3072): s_u[8][128]
    for (int idx = t; idx < 8*208; idx += 512) {
        int g = idx / 208, k = idx - g*208;
        float v;
        if (k < FDIM_) v = feat_h[(node0 + g)*FS_ + k];
        else           v = s_mr[g][k - FDIM_];
        su[g*208 + k] = v;
    }
    __syncthreads();
    // u = silu(s_in @ Wn1 + bn1): 8 rows x 128 cols = 1024 tasks, 2 passes, k=207
    {
        const float* Wn1l = Wn1 + l*NDIM_*HID_;
        #pragma unroll
        for (int pass = 0; pass < 2; ++pass) {
            int task = pass*512 + t;
            int g = task >> 7, c = task & 127;
            const float* sp = su + g*208;
            const float* wp = Wn1l + c;
            float acc = 0.f;
            #pragma unroll 8
            for (int k = 0; k < NDIM_; ++k)
                acc += sp[k] * wp[(size_t)k*HID_];
            su[2048 + task] = silu_(acc + bn1[l*HID_ + c]);
        }
    }
    __syncthreads();
    // feat += u @ Wn2 + bn2: 8 rows x 128 cols (guard c<79), 2 passes, k=128
    {
        const float* Wn2l = Wn2 + l*HID_*FDIM_;
        #pragma unroll
        for (int pass = 0; pass < 2; ++pass) {
            int task = pass*512 + t;
            int g = task >> 7, c = task & 127;
            if (c < FDIM_) {
                const float* up = su + 2048 + g*HID_;
                const float* wp = Wn2l + c;
                float acc = bn2[l*FDIM_ + c];
                #pragma unroll 8
                for (int k = 0; k < HID_; ++k)
                    acc += up[k] * wp[(size_t)k*FDIM_];
                float nf = su[g*208 + c] + acc;
                feat_h[(node0 + g)*FS_ + c] = nf;
                su[g*208 + c] = nf;
            }
        }
    }
    // x-update / output (independent of Wn2 phase data)
    if (t < 24) {
        int g = t / 3, d = t - (t/3)*3;
        int ng = node0 + g;
        int bsg = ng / H_, hg = ng - bsg*H_;
        float xv = xin[(bsg*NN_ + hg)*4 + d] + s_xr[g][d];
        if (do_w1) {
            xout[(bsg*NN_ + hg)*4 + d] = xv;       // x1 h-rows for layer 1
        } else {
            int bg = bsg / S_;
            out[ng*3 + d] = (xv - x0h[ng*4 + d]) * amask[bg*H_ + hg];
        }
    }
    if (!do_w1) return;
    __syncthreads();
    // next-layer W1 projections from updated feat: 2 sel x 8 rows x 128 = 2048 tasks
    {
        const float* W1n = W1 + EDIM_*HID_;        // layer 1
        #pragma unroll
        for (int pass = 0; pass < 4; ++pass) {
            int task = pass*512 + t;
            int c = task & 127, g = (task >> 7) & 7, sel = task >> 10;
            const float* sp = su + g*208;
            const float* wp = W1n + (size_t)(sel ? FDIM_ : 0)*HID_ + c;
            float acc = 0.f;
            #pragma unroll 8
            for (int f = 0; f < FDIM_; ++f)
                acc += sp[f] * wp[(size_t)f*HID_];
            int ng = node0 + g;
            if (sel == 0) {
                int bg = (ng / H_) / S_;
                hiW1w[(size_t)(1600 + ng)*HID_ + c] =
                    acc + b1[HID_ + c] + t_in[bg]*W1n[160*HID_ + c];
            } else {
                hjW1w[(size_t)(4800 + ng)*HID_ + c] = acc;
            }
        }
    }
}

// ---------------- launch ----------------
extern "C" void kernel_launch(void* const* d_in, const int* in_sizes, int n_in,
                              void* d_out, int out_size, void* d_ws, size_t ws_size,
                              hipStream_t stream)
{
    const float* t_in  = (const float*)d_in[0];
    const float* x_h   = (const float*)d_in[1];
    const float* x_hv  = (const float*)d_in[2];
    const float* bond  = (const float*)d_in[3];
    const float* em_hv = (const float*)d_in[4];
    const float* em_hh = (const float*)d_in[5];
    const float* amask = (const float*)d_in[6];
    const float* W1    = (const float*)d_in[7];
    const float* b1    = (const float*)d_in[8];
    const float* W2    = (const float*)d_in[9];
    const float* b2    = (const float*)d_in[10];
    const float* Wc1   = (const float*)d_in[11];
    const float* bc1   = (const float*)d_in[12];
    const float* Wc2   = (const float*)d_in[13];
    const float* Wn1   = (const float*)d_in[14];
    const float* bn1   = (const float*)d_in[15];
    const float* Wn2   = (const float*)d_in[16];
    const float* bn2   = (const float*)d_in[17];
    const int* pep     = (const int*)d_in[18];
    const int* lab_hv  = (const int*)d_in[19];
    const int* lab_h   = (const int*)d_in[20];
    const int* pos_hv  = (const int*)d_in[21];
    const int* pos_h   = (const int*)d_in[22];
    const int* ehh     = (const int*)d_in[23];
    const int* bound   = (const int*)d_in[24];

    float* ws     = (float*)d_ws;
    float* feat_h = ws + OFF_FEATH;
    float* x0     = ws + OFF_X0;
    float* x1     = ws + OFF_X1;
    float* x0h    = ws + OFF_X0H;
    int*   hhcol  = (int*)(ws + OFF_HHCOL);
    float* hhem   = ws + OFF_HHEM;
    int*   hhoff  = (int*)(ws + OFF_HHOFF);
    float* hiW1   = ws + OFF_HIW1;
    float* hjW1   = ws + OFF_HJW1;
    unsigned short* Wp = (unsigned short*)(ws + OFF_WP);

    hipLaunchKernelGGL(k_setup, dim3(SETUP_BLKS_), dim3(256), 0, stream,
                       x_h, x_hv, bound, ehh, em_hh,
                       W1, b1, t_in, W2, Wc1,
                       lab_h, pos_h, lab_hv, pos_hv, pep,
                       feat_h, x0, x1, x0h, hhcol, hhem, hhoff,
                       hiW1, hjW1, Wp);

    hipLaunchKernelGGL(k_edge_mlp, dim3(NROW_/8), dim3(512), 0, stream,
                       x0, hiW1, hjW1, hhcol, hhem, hhoff, em_hv, bond,
                       W1, b2, bc1, Wc2, Wp, 0,
                       Wn1, bn1, Wn2, bn2, b1, t_in,
                       feat_h, x1, hiW1, hjW1, x0h, amask,
                       (float*)d_out, 1);

    hipLaunchKernelGGL(k_edge_mlp, dim3(NROW_/8), dim3(512), 0, stream,
                       x1, hiW1, hjW1, hhcol, hhem, hhoff, em_hv, bond,
                       W1, b2, bc1, Wc2, Wp, 1,
                       Wn1, bn1, Wn2, bn2, b1, t_in,
                       feat_h, x1, hiW1, hjW1, x0h, amask,
                       (float*)d_out, 0);
}

// Round 18
// 316.422 us; speedup vs baseline: 1.0255x; 1.0255x over previous
//
#include <hip/hip_runtime.h>
#include <math.h>

// Problem constants
#define B_     8
#define S_     4
#define H_     50
#define NH_    200
#define EHH_   400
#define L_     2
#define HID_   128
#define FDIM_  79          // 44 + 20 + 15
#define EDIM_  161         // 2*FDIM + 3
#define NN_    250         // H + NH
#define NROW_  1600        // BS*H
#define BS_    32          // B*S
#define FS_    80          // feat row stride
#define MSTR_  136         // s_m stride in bf16 (128 + 8)
#define NDIM_  207         // FDIM + HID
#define HVB_   1600        // hjW1 heavy-region base row

// Workspace layout (float offsets) — double-buffered across layers:
//   x0 (l0 reads) -> x1 (l0 tail writes h-rows; l1 reads)
//   hiW1 rows [0,1600)=l0 (setup), [1600,3200)=l1 (l0 tail)
//   hjW1 rows [0,1600)=h l0 (setup), [1600,3200)=hv l0, [3200,4800)=hv l1 (setup),
//             [4800,6400)=h l1 (l0 tail)
#define OFF_FEATH  0         // 128000
#define OFF_X0     128000    // 32000
#define OFF_X1     160000    // 32000
#define OFF_X0H    192000    // 6400
#define OFF_HHCOL  198400    // 3200 (int)
#define OFF_HHEM   201600    // 3200
#define OFF_HHOFF  204800    // 512 (int)
#define OFF_HIW1   205312    // 3200*128 = 409600
#define OFF_HJW1   614912    // 6400*128 = 819200
#define OFF_WP     1434112   // 65536 ushort (16B-aligned)

typedef __attribute__((ext_vector_type(8))) short short8;
typedef __attribute__((ext_vector_type(4))) float f32x4;

__device__ __forceinline__ float silu_(float v) {
    return v * __builtin_amdgcn_rcpf(1.0f + __expf(-v));
}
__device__ __forceinline__ unsigned short f2bf(float f) {
    unsigned int u = __float_as_uint(f);
    unsigned int r = (u + 0x7fffu + ((u >> 16) & 1u)) >> 16;
    return (unsigned short)r;
}

// ================= fused setup (compacted: 4 elements/thread, grid 562) =================
#define HV_BLKS_    400    // 409600 / 1024
#define PACK_BLKS_  64     // 65536 / 1024
#define SORT_BLKS_  8      // counting-sort hh edges by row, per b; emits CSR
#define HROW_BLKS_  50     // 51200 / 1024
#define FEAT_BLKS_  32     // ceil(32000 / 1024)
#define XI_BLKS_    8      // ceil(8000 / 1024)
#define SETUP_BLKS_ (HV_BLKS_ + PACK_BLKS_ + SORT_BLKS_ + HROW_BLKS_ + FEAT_BLKS_ + XI_BLKS_)

__global__ __launch_bounds__(256) void k_setup(
    const float* __restrict__ x_h, const float* __restrict__ x_hv,
    const int* __restrict__ bound,
    const int* __restrict__ ehh, const float* __restrict__ em_hh,
    const float* __restrict__ W1, const float* __restrict__ b1,
    const float* __restrict__ t_in,
    const float* __restrict__ W2, const float* __restrict__ Wc1,
    const int* __restrict__ lab_h, const int* __restrict__ pos_h,
    const int* __restrict__ lab_hv, const int* __restrict__ pos_hv,
    const int* __restrict__ pep,
    float* __restrict__ feat_h,
    float* __restrict__ x0, float* __restrict__ x1, float* __restrict__ x0h,
    int* __restrict__ hhcol, float* __restrict__ hhem, int* __restrict__ hhoff,
    float* __restrict__ hiW1, float* __restrict__ hjW1,
    unsigned short* __restrict__ Wp)
{
    int blk = blockIdx.x, t = threadIdx.x;
    if (blk < HV_BLKS_) {
        #pragma unroll
        for (int i = 0; i < 4; ++i) {
            int g = blk*1024 + i*256 + t;    // [0, 409600)
            int l = g / 204800;
            int r = g - l*204800;
            int node = r >> 7, col = r & 127;    // node = b*NH + nh
            int b = node / NH_;
            int label = lab_hv[node], pos = pos_hv[node];
            int aa = pep[b*15 + pos - 1];
            const float* W1l = W1 + l*EDIM_*HID_;
            float hj = W1l[(FDIM_ + label)*HID_ + col]
                     + W1l[(FDIM_ + 44 + aa)*HID_ + col]
                     + W1l[(FDIM_ + 64 + pos - 1)*HID_ + col];
            hjW1[(size_t)(HVB_ + l*1600 + node)*HID_ + col] = hj;
        }
        return;
    }
    blk -= HV_BLKS_;
    if (blk < PACK_BLKS_) {
        // Pack W2/Wc1: ushort idx in a 16384 chunk = ((kc*8+nt)*64 + lane)*8 + j
        // -> a wave's (kc,nt) B-fragment read is one contiguous 1024B line.
        #pragma unroll
        for (int i = 0; i < 4; ++i) {
            int g = blk*1024 + i*256 + t;    // [0, 65536)
            int idx = g & 16383;
            int lm  = g >> 14;
            int l = lm >> 1, mat = lm & 1;
            int j   = idx & 7;
            int l15 = (idx >> 3) & 15;
            int qq  = (idx >> 7) & 3;
            int nt  = (idx >> 9) & 7;
            int kc  = (idx >> 12) & 3;
            int n = nt*16 + l15;
            int k = kc*32 + qq*8 + j;
            const float* W = (mat == 0 ? W2 : Wc1) + l*HID_*HID_;
            Wp[g] = f2bf(W[k*HID_ + n]);
        }
        return;
    }
    blk -= PACK_BLKS_;
    if (blk < SORT_BLKS_) {
        // counting-sort the 400 hh edges of batch b by row; emit CSR offsets
        int b = blk;
        __shared__ int scnt[64];
        __shared__ int srow[EHH_], scol[EHH_];
        __shared__ float sem[EHH_];
        if (t < 64) scnt[t] = 0;
        __syncthreads();
        for (int e = t; e < EHH_; e += 256) {
            int r = ehh[(b*EHH_ + e)*2 + 0];
            srow[e] = r;
            scol[e] = ehh[(b*EHH_ + e)*2 + 1];
            sem[e]  = em_hh[b*EHH_ + e];
            atomicAdd(&scnt[r], 1);
        }
        __syncthreads();
        if (t == 0) {
            int acc = 0;
            for (int i = 0; i < H_; ++i) { int v = scnt[i]; scnt[i] = acc; acc += v; }
        }
        __syncthreads();
        if (t < 51) hhoff[b*64 + t] = (t < H_) ? scnt[t] : EHH_;
        __syncthreads();
        for (int e = t; e < EHH_; e += 256) {
            int r = srow[e];
            int pos = atomicAdd(&scnt[r], 1);
            hhcol[b*EHH_ + pos] = scol[e];
            hhem [b*EHH_ + pos] = sem[e];
        }
        return;
    }
    blk -= SORT_BLKS_;
    if (blk < HROW_BLKS_) {
        // h-node layer-0 projections; fold b1 and t*w160 into hiW1
        #pragma unroll
        for (int i = 0; i < 4; ++i) {
            int g = blk*1024 + i*256 + t;    // [0, 51200)
            int node = g >> 7, col = g & 127;    // node = b*H + h
            int b = node / H_;
            int label = lab_h[node], pos = pos_h[node];
            int aa = pep[b*15 + pos - 1];
            const float* W1l = W1;               // layer 0
            float hi = W1l[label*HID_ + col]
                     + W1l[(44 + aa)*HID_ + col]
                     + W1l[(64 + pos - 1)*HID_ + col]
                     + b1[col]
                     + t_in[b] * W1l[160*HID_ + col];
            float hj = W1l[(FDIM_ + label)*HID_ + col]
                     + W1l[(FDIM_ + 44 + aa)*HID_ + col]
                     + W1l[(FDIM_ + 64 + pos - 1)*HID_ + col];
            int h = node % H_;
            #pragma unroll
            for (int s = 0; s < S_; ++s) {
                int row = (b*S_ + s)*H_ + h;
                hiW1[(size_t)row*HID_ + col] = hi;
                hjW1[(size_t)row*HID_ + col] = hj;
            }
        }
        return;
    }
    blk -= HROW_BLKS_;
    if (blk < FEAT_BLKS_) {
        #pragma unroll
        for (int i = 0; i < 4; ++i) {
            int g = blk*1024 + i*256 + t;    // [0, 32768) guard 32000
            if (g < 32000) {
                int node = g / FS_, f = g % FS_;     // node = b*H + h
                int b = node / H_, h = node % H_;
                int label = lab_h[node], pos = pos_h[node];
                int aa = pep[b*15 + pos - 1];
                float v = 0.f;
                if (f < 44)      v = (f == label)          ? 1.0f : 0.0f;
                else if (f < 64) v = ((f - 44) == aa)      ? 1.0f : 0.0f;
                else if (f < 79) v = ((f - 64) == pos - 1) ? 1.0f : 0.0f;
                #pragma unroll
                for (int s = 0; s < S_; ++s)
                    feat_h[((b*S_ + s)*H_ + h)*FS_ + f] = v;
            }
        }
        return;
    }
    blk -= FEAT_BLKS_;
    {
        #pragma unroll
        for (int i = 0; i < 4; ++i) {
            int g = blk*1024 + i*256 + t;    // [0, 8192) guard 8000
            if (g < BS_*NN_) {
                int bs = g / NN_, n = g % NN_;
                int b = bs / S_;
                if (n < H_) {
                    int ba = bound[b*H_ + n];
                    for (int d = 0; d < 3; ++d) {
                        float v = x_h[(bs*H_ + n)*3 + d] + x_hv[(b*NH_ + ba)*3 + d];
                        x0[g*4 + d] = v;
                        x0h[(bs*H_ + n)*4 + d] = v;
                    }
                } else {
                    int nh = n - H_;
                    for (int d = 0; d < 3; ++d) {
                        float v = x_hv[(b*NH_ + nh)*3 + d];
                        x0[g*4 + d] = v;
                        x1[g*4 + d] = v;         // heavy rows never change
                    }
                }
            }
        }
    }
}

// ============ per-layer: 8 rows/block, one wave per row; fused node-update tail ============
// Structure FROZEN (verified 322.2/322.7/323.8 us). This round's single variable:
// T5 s_setprio(1)/(0) around the stage-2/3 MFMA clusters. Mechanism: 8 independent
// row-waves per block (no intra-loop barriers) sit at DIFFERENT phases on their
// SIMDs; setprio lets the CU scheduler favor the MFMA-entering wave while its
// SIMD-mate issues gathers/prefetch (catalog T5: +4-7% in this regime, null in
// barrier-lockstep kernels). Zero register/LDS/correctness surface.
__global__ __launch_bounds__(512) void k_edge_mlp(
    const float* __restrict__ xin, const float* __restrict__ hiW1g,
    const float* __restrict__ hjW1,
    const int* __restrict__ hhcol, const float* __restrict__ hhem,
    const int* __restrict__ hhoff,
    const float* __restrict__ em_hv, const float* __restrict__ bond_in,
    const float* __restrict__ W1,
    const float* __restrict__ b2, const float* __restrict__ bc1,
    const float* __restrict__ Wc2,
    const unsigned short* __restrict__ Wp, int l,
    const float* __restrict__ Wn1, const float* __restrict__ bn1,
    const float* __restrict__ Wn2, const float* __restrict__ bn2,
    const float* __restrict__ b1, const float* __restrict__ t_in,
    float* __restrict__ feat_h, float* __restrict__ xout,
    float* __restrict__ hiW1w, float* __restrict__ hjW1w,
    const float* __restrict__ x0h, const float* __restrict__ amask,
    float* __restrict__ out, int do_w1)
{
    __shared__ unsigned short s_wp[2*16384];       // 65536 B; fp32 scratch in tail
    __shared__ unsigned short s_m[8][16][MSTR_];   // 34816 B, wave-private 16-row chunks
    __shared__ float s_hi[8][HID_];                // 4096 B: per-row hiW1
    __shared__ float s_cc[5][HID_];                // W1r158, W1r159, b2, bc1, Wc2
    __shared__ float s_mr[8][HID_];                // 4096 B: per-row aggm
    __shared__ float s_xr[8][4];                   // per-row aggx

    const int t = threadIdx.x, lane = t & 63, w = t >> 6;
    const int l15 = lane & 15, q = lane >> 4;
    const int node0 = blockIdx.x*8;
    const int node  = node0 + w;                   // this wave's row (bs*H + h)
    const int bs = node / H_, h = node - bs*H_;
    const int b  = bs / S_;
    const int hb = (l ? 4800 : 0) + bs*H_;         // hjW1 h-region base for this layer

    // ---- stage weights Wp2|Wp3 (contiguous 64 KB) into LDS ----
    {
        const float4* src = (const float4*)(Wp + (size_t)l*32768);
        float4* dst = (float4*)s_wp;
        #pragma unroll
        for (int i = 0; i < 8; ++i) dst[t + i*512] = src[t + i*512];
    }
    const float* W1l = W1 + l*EDIM_*HID_;
    #pragma unroll
    for (int i = 0; i < 2; ++i) {
        int idx = i*512 + t;                       // [0,1024): 8 rows x 128 cols
        int g = idx >> 7, c = idx & 127;
        s_hi[g][c] = hiW1g[(size_t)(l*1600 + node0 + g)*HID_ + c];
    }
    if (t < 128) {
        s_cc[0][t] = W1l[158*HID_ + t];
        s_cc[1][t] = W1l[159*HID_ + t];
        s_cc[2][t] = b2 [l*HID_ + t];
        s_cc[3][t] = bc1[l*HID_ + t];
        s_cc[4][t] = Wc2[l*HID_ + t];
    }

    const int hh0 = hhoff[b*64 + h];
    const int cnt = hhoff[b*64 + h + 1] - hh0;
    const int E   = cnt + NH_;                     // total real edges for this row
    const int NT  = (E + 15) >> 4;                 // 16-edge tiles (13..14)

    const float xi0 = xin[(bs*NN_ + h)*4 + 0];
    const float xi1 = xin[(bs*NN_ + h)*4 + 1];
    const float xi2 = xin[(bs*NN_ + h)*4 + 2];

    // per-lane edge-scalar gather (executed by lanes 0..15 only)
    auto gather = [&](int e, float& d0, float& d1, float& d2,
                      float& dist, float& bnd, float& em, int& jj) {
        if (e < E) {
            int col;
            if (e < cnt) {                         // sorted hh edge
                col = hhcol[b*EHH_ + hh0 + e];
                em  = hhem [b*EHH_ + hh0 + e];
                jj  = hb + col;
            } else {                               // grid edge (row h -> heavy cc)
                int cc = e - cnt;
                col = H_ + cc;
                em  = em_hv [(b*H_ + h)*NH_ + cc];
                bnd = bond_in[(b*H_ + h)*NH_ + cc];
                jj  = HVB_ + l*1600 + b*NH_ + cc;
            }
            d0 = xi0 - xin[(bs*NN_ + col)*4 + 0];
            d1 = xi1 - xin[(bs*NN_ + col)*4 + 1];
            d2 = xi2 - xin[(bs*NN_ + col)*4 + 2];
            dist = sqrtf(d0*d0 + d1*d1 + d2*d2);
        }
    };

    float macc[8] = {0.f,0.f,0.f,0.f,0.f,0.f,0.f,0.f};
    float xacc = 0.f;
    __syncthreads();                               // s_wp/s_hi/s_cc ready

    // ---- pipeline prologue: tile 0 ----
    float cd0=0.f, cd1=0.f, cd2=0.f, cdist=0.f, cbnd=0.f, cem=0.f;
    int   cjj = hb;                                // padding: valid row, em=0
    if (lane < 16) gather(lane, cd0, cd1, cd2, cdist, cbnd, cem, cjj);
    float distb = __shfl(cdist, l15, 64);
    float bndb  = __shfl(cbnd,  l15, 64);
    int   jjb   = __shfl(cjj,   l15, 64);
    float4 pr[8];
    {
        const float* pj = hjW1 + (size_t)jjb*HID_ + q*8;
        #pragma unroll
        for (int kc = 0; kc < 4; ++kc) {
            pr[2*kc]   = *(const float4*)(pj + kc*32);
            pr[2*kc+1] = *(const float4*)(pj + kc*32 + 4);
        }
    }

    for (int ti = 0; ti < NT; ++ti) {
        const int nx = ti + 1;
        const bool hasNext = (nx < NT);            // wave-uniform

        // ---- gather NEXT tile's scalars (registers only) ----
        float nd0=0.f, nd1=0.f, nd2=0.f, ndist=0.f, nbnd=0.f, nem=0.f;
        int   njj = hb;
        if (hasNext && lane < 16)
            gather(nx*16 + lane, nd0, nd1, nd2, ndist, nbnd, nem, njj);

        // ---- stage 1: m1 = silu(hi + hj + dist*w158 + bond*w159) ----
        short8 afrag[4];
        #pragma unroll
        for (int kc = 0; kc < 4; ++kc) {
            int k0 = kc*32 + q*8;
            float4 c0 = pr[2*kc];
            float4 c1 = pr[2*kc+1];
            float4 h0 = *(const float4*)&s_hi[w][k0];
            float4 h1 = *(const float4*)&s_hi[w][k0 + 4];
            float4 wa0= *(const float4*)&s_cc[0][k0];
            float4 wa1= *(const float4*)&s_cc[0][k0 + 4];
            float4 wb0= *(const float4*)&s_cc[1][k0];
            float4 wb1= *(const float4*)&s_cc[1][k0 + 4];
            short8 fr;
            fr[0] = (short)f2bf(silu_(h0.x + c0.x + distb*wa0.x + bndb*wb0.x));
            fr[1] = (short)f2bf(silu_(h0.y + c0.y + distb*wa0.y + bndb*wb0.y));
            fr[2] = (short)f2bf(silu_(h0.z + c0.z + distb*wa0.z + bndb*wb0.z));
            fr[3] = (short)f2bf(silu_(h0.w + c0.w + distb*wa0.w + bndb*wb0.w));
            fr[4] = (short)f2bf(silu_(h1.x + c1.x + distb*wa1.x + bndb*wb1.x));
            fr[5] = (short)f2bf(silu_(h1.y + c1.y + distb*wa1.y + bndb*wb1.y));
            fr[6] = (short)f2bf(silu_(h1.z + c1.z + distb*wa1.z + bndb*wb1.z));
            fr[7] = (short)f2bf(silu_(h1.w + c1.w + distb*wa1.w + bndb*wb1.w));
            afrag[kc] = fr;
        }

        // ---- issue NEXT tile's hjW1 loads (hide under stage 2/3 MFMA) ----
        float ndistb = 0.f, nbndb = 0.f;
        if (hasNext) {
            ndistb = __shfl(ndist, l15, 64);
            nbndb  = __shfl(nbnd,  l15, 64);
            int njjb = __shfl(njj, l15, 64);
            const float* pj = hjW1 + (size_t)njjb*HID_ + q*8;
            #pragma unroll
            for (int kc = 0; kc < 4; ++kc) {
                pr[2*kc]   = *(const float4*)(pj + kc*32);
                pr[2*kc+1] = *(const float4*)(pj + kc*32 + 4);
            }
        }

        // ---- stage 2: m = silu(m1 @ W2 + b2) * emask (T5: prio up in MFMA region) ----
        float em4[4];
        #pragma unroll
        for (int rr = 0; rr < 4; ++rr) em4[rr] = __shfl(cem, q*4 + rr, 64);
        __builtin_amdgcn_s_setprio(1);
        #pragma unroll
        for (int nt = 0; nt < 8; ++nt) {
            float bias = s_cc[2][nt*16 + l15];
            f32x4 c = {bias, bias, bias, bias};
            #pragma unroll
            for (int kc = 0; kc < 4; ++kc) {
                short8 bf = *(const short8*)&s_wp[((kc*8 + nt)*64 + lane)*8];
                c = __builtin_amdgcn_mfma_f32_16x16x32_bf16(afrag[kc], bf, c, 0, 0, 0);
            }
            #pragma unroll
            for (int rr = 0; rr < 4; ++rr) {
                float mv = silu_(c[rr]) * em4[rr]; // padding edges have em=0 -> mv=0
                s_m[w][q*4 + rr][nt*16 + l15] = f2bf(mv);
                macc[nt] += mv;
            }
        }
        __builtin_amdgcn_s_setprio(0);
        __builtin_amdgcn_wave_barrier();           // s_m write -> read, wave-private

        // ---- stage 3: cw = silu(m @ Wc1 + bc1) @ Wc2 (T5: prio up in MFMA region) ----
        short8 af2[4];
        #pragma unroll
        for (int kc = 0; kc < 4; ++kc)
            af2[kc] = *(const short8*)&s_m[w][l15][kc*32 + q*8];
        float p[4] = {0.f, 0.f, 0.f, 0.f};
        __builtin_amdgcn_s_setprio(1);
        #pragma unroll
        for (int nt = 0; nt < 8; ++nt) {
            float bias = s_cc[3][nt*16 + l15];
            f32x4 c = {bias, bias, bias, bias};
            #pragma unroll
            for (int kc = 0; kc < 4; ++kc) {
                short8 bf = *(const short8*)&s_wp[16384 + ((kc*8 + nt)*64 + lane)*8];
                c = __builtin_amdgcn_mfma_f32_16x16x32_bf16(af2[kc], bf, c, 0, 0, 0);
            }
            float wcv = s_cc[4][nt*16 + l15];
            #pragma unroll
            for (int rr = 0; rr < 4; ++rr)
                p[rr] += silu_(c[rr]) * wcv;
        }
        __builtin_amdgcn_s_setprio(0);
        #pragma unroll
        for (int m = 1; m < 16; m <<= 1) {
            #pragma unroll
            for (int rr = 0; rr < 4; ++rr) p[rr] += __shfl_xor(p[rr], m, 64);
        }
        #pragma unroll
        for (int rr = 0; rr < 4; ++rr) {
            float sd0 = __shfl(cd0, q*4 + rr, 64);
            float sd1 = __shfl(cd1, q*4 + rr, 64);
            float sd2 = __shfl(cd2, q*4 + rr, 64);
            if (l15 < 3) {
                float dsel = (l15 == 0) ? sd0 : ((l15 == 1) ? sd1 : sd2);
                xacc += dsel * p[rr];
            }
        }
        __builtin_amdgcn_wave_barrier();           // stage-3 s_m reads before next write

        // ---- rotate pipeline registers ----
        cd0 = nd0; cd1 = nd1; cd2 = nd2; cem = nem;
        distb = ndistb; bndb = nbndb;
    }

    // ---- intra-wave combine (wave == row: no cross-wave step) ----
    #pragma unroll
    for (int nt = 0; nt < 8; ++nt) {
        macc[nt] += __shfl_xor(macc[nt], 16, 64);
        macc[nt] += __shfl_xor(macc[nt], 32, 64);
    }
    if (q == 0) {
        #pragma unroll
        for (int nt = 0; nt < 8; ++nt) s_mr[w][nt*16 + l15] = macc[nt];
    }
    xacc += __shfl_xor(xacc, 16, 64);
    xacc += __shfl_xor(xacc, 32, 64);
    if (q == 0 && l15 < 3) s_xr[w][l15] = xacc;
    __syncthreads();                               // edge work done; s_wp now dead

    // ================= FUSED node update (8 rows, 512 threads) =================
    // Full-width GEMV tasks (no k-split): compile-time trip counts + unroll 8.
    float* su = (float*)s_wp;                      // 16384 floats of scratch
    // su[0..1664): s_in[8][208] | su[2048..3072): s_u[8][128]
    for (int idx = t; idx < 8*208; idx += 512) {
        int g = idx / 208, k = idx - g*208;
        float v;
        if (k < FDIM_) v = feat_h[(node0 + g)*FS_ + k];
        else           v = s_mr[g][k - FDIM_];
        su[g*208 + k] = v;
    }
    __syncthreads();
    // u = silu(s_in @ Wn1 + bn1): 8 rows x 128 cols = 1024 tasks, 2 passes, k=207
    {
        const float* Wn1l = Wn1 + l*NDIM_*HID_;
        #pragma unroll
        for (int pass = 0; pass < 2; ++pass) {
            int task = pass*512 + t;
            int g = task >> 7, c = task & 127;
            const float* sp = su + g*208;
            const float* wp = Wn1l + c;
            float acc = 0.f;
            #pragma unroll 8
            for (int k = 0; k < NDIM_; ++k)
                acc += sp[k] * wp[(size_t)k*HID_];
            su[2048 + task] = silu_(acc + bn1[l*HID_ + c]);
        }
    }
    __syncthreads();
    // feat += u @ Wn2 + bn2: 8 rows x 128 cols (guard c<79), 2 passes, k=128
    {
        const float* Wn2l = Wn2 + l*HID_*FDIM_;
        #pragma unroll
        for (int pass = 0; pass < 2; ++pass) {
            int task = pass*512 + t;
            int g = task >> 7, c = task & 127;
            if (c < FDIM_) {
                const float* up = su + 2048 + g*HID_;
                const float* wp = Wn2l + c;
                float acc = bn2[l*FDIM_ + c];
                #pragma unroll 8
                for (int k = 0; k < HID_; ++k)
                    acc += up[k] * wp[(size_t)k*FDIM_];
                float nf = su[g*208 + c] + acc;
                feat_h[(node0 + g)*FS_ + c] = nf;
                su[g*208 + c] = nf;
            }
        }
    }
    // x-update / output (independent of Wn2 phase data)
    if (t < 24) {
        int g = t / 3, d = t - (t/3)*3;
        int ng = node0 + g;
        int bsg = ng / H_, hg = ng - bsg*H_;
        float xv = xin[(bsg*NN_ + hg)*4 + d] + s_xr[g][d];
        if (do_w1) {
            xout[(bsg*NN_ + hg)*4 + d] = xv;       // x1 h-rows for layer 1
        } else {
            int bg = bsg / S_;
            out[ng*3 + d] = (xv - x0h[ng*4 + d]) * amask[bg*H_ + hg];
        }
    }
    if (!do_w1) return;
    __syncthreads();
    // next-layer W1 projections from updated feat: 2 sel x 8 rows x 128 = 2048 tasks
    {
        const float* W1n = W1 + EDIM_*HID_;        // layer 1
        #pragma unroll
        for (int pass = 0; pass < 4; ++pass) {
            int task = pass*512 + t;
            int c = task & 127, g = (task >> 7) & 7, sel = task >> 10;
            const float* sp = su + g*208;
            const float* wp = W1n + (size_t)(sel ? FDIM_ : 0)*HID_ + c;
            float acc = 0.f;
            #pragma unroll 8
            for (int f = 0; f < FDIM_; ++f)
                acc += sp[f] * wp[(size_t)f*HID_];
            int ng = node0 + g;
            if (sel == 0) {
                int bg = (ng / H_) / S_;
                hiW1w[(size_t)(1600 + ng)*HID_ + c] =
                    acc + b1[HID_ + c] + t_in[bg]*W1n[160*HID_ + c];
            } else {
                hjW1w[(size_t)(4800 + ng)*HID_ + c] = acc;
            }
        }
    }
}

// ---------------- launch ----------------
extern "C" void kernel_launch(void* const* d_in, const int* in_sizes, int n_in,
                              void* d_out, int out_size, void* d_ws, size_t ws_size,
                              hipStream_t stream)
{
    const float* t_in  = (const float*)d_in[0];
    const float* x_h   = (const float*)d_in[1];
    const float* x_hv  = (const float*)d_in[2];
    const float* bond  = (const float*)d_in[3];
    const float* em_hv = (const float*)d_in[4];
    const float* em_hh = (const float*)d_in[5];
    const float* amask = (const float*)d_in[6];
    const float* W1    = (const float*)d_in[7];
    const float* b1    = (const float*)d_in[8];
    const float* W2    = (const float*)d_in[9];
    const float* b2    = (const float*)d_in[10];
    const float* Wc1   = (const float*)d_in[11];
    const float* bc1   = (const float*)d_in[12];
    const float* Wc2   = (const float*)d_in[13];
    const float* Wn1   = (const float*)d_in[14];
    const float* bn1   = (const float*)d_in[15];
    const float* Wn2   = (const float*)d_in[16];
    const float* bn2   = (const float*)d_in[17];
    const int* pep     = (const int*)d_in[18];
    const int* lab_hv  = (const int*)d_in[19];
    const int* lab_h   = (const int*)d_in[20];
    const int* pos_hv  = (const int*)d_in[21];
    const int* pos_h   = (const int*)d_in[22];
    const int* ehh     = (const int*)d_in[23];
    const int* bound   = (const int*)d_in[24];

    float* ws     = (float*)d_ws;
    float* feat_h = ws + OFF_FEATH;
    float* x0     = ws + OFF_X0;
    float* x1     = ws + OFF_X1;
    float* x0h    = ws + OFF_X0H;
    int*   hhcol  = (int*)(ws + OFF_HHCOL);
    float* hhem   = ws + OFF_HHEM;
    int*   hhoff  = (int*)(ws + OFF_HHOFF);
    float* hiW1   = ws + OFF_HIW1;
    float* hjW1   = ws + OFF_HJW1;
    unsigned short* Wp = (unsigned short*)(ws + OFF_WP);

    hipLaunchKernelGGL(k_setup, dim3(SETUP_BLKS_), dim3(256), 0, stream,
                       x_h, x_hv, bound, ehh, em_hh,
                       W1, b1, t_in, W2, Wc1,
                       lab_h, pos_h, lab_hv, pos_hv, pep,
                       feat_h, x0, x1, x0h, hhcol, hhem, hhoff,
                       hiW1, hjW1, Wp);

    hipLaunchKernelGGL(k_edge_mlp, dim3(NROW_/8), dim3(512), 0, stream,
                       x0, hiW1, hjW1, hhcol, hhem, hhoff, em_hv, bond,
                       W1, b2, bc1, Wc2, Wp, 0,
                       Wn1, bn1, Wn2, bn2, b1, t_in,
                       feat_h, x1, hiW1, hjW1, x0h, amask,
                       (float*)d_out, 1);

    hipLaunchKernelGGL(k_edge_mlp, dim3(NROW_/8), dim3(512), 0, stream,
                       x1, hiW1, hjW1, hhcol, hhem, hhoff, em_hv, bond,
                       W1, b2, bc1, Wc2, Wp, 1,
                       Wn1, bn1, Wn2, bn2, b1, t_in,
                       feat_h, x1, hiW1, hjW1, x0h, amask,
                       (float*)d_out, 0);
}